// Round 1
// baseline (365.430 us; speedup 1.0000x reference)
//
#include <hip/hip_runtime.h>

#define N_NODES 100000
#define N_EDGES 1600000
#define IN_DIM 256
#define HIDDEN 128
#define OUT_DIM 64

#define NBIN 391       // coarse bins of 256 nodes: ceil(100000/256)
#define NBLK3 256      // histogram/scatter blocks
#define CHUNK 6250     // edges per block: N_EDGES / NBLK3 exactly
#define NMAT (NBIN * NBLK3)      // 100096 = scan length
#define NBLK_SCAN (NMAT / 256)   // 391 exactly
#define CAP 6144       // max edges per bin (mean 4096, sigma 64 -> 32 sigma margin)

typedef __bf16 bf16x8 __attribute__((ext_vector_type(8)));
typedef __bf16 bf16x4 __attribute__((ext_vector_type(4)));
typedef float f32x4 __attribute__((ext_vector_type(4)));

// ---------------------------------------------------------------------------
// P1: per-(bin,block) histogram. cnt2[k*NBLK3 + b] = #edges of block b in bin k
// ---------------------------------------------------------------------------
__launch_bounds__(256)
__global__ void k_hist(const int* __restrict__ dst, int* __restrict__ cnt2) {
    __shared__ int hist[NBIN];
    for (int i = threadIdx.x; i < NBIN; i += 256) hist[i] = 0;
    __syncthreads();
    int base = blockIdx.x * CHUNK;
    for (int i = threadIdx.x; i < CHUNK; i += 256)
        atomicAdd(&hist[dst[base + i] >> 8], 1);
    __syncthreads();
    for (int k = threadIdx.x; k < NBIN; k += 256)
        cnt2[k * NBLK3 + blockIdx.x] = hist[k];
}

// ---------------------------------------------------------------------------
// P2: 3-kernel exclusive scan over cnt2 (in place), length NMAT
// ---------------------------------------------------------------------------
__global__ void k_scan1(int* __restrict__ a, int* __restrict__ bsum) {
    __shared__ int tmp[256];
    int t = threadIdx.x;
    int i = blockIdx.x * 256 + t;
    int v = a[i];
    tmp[t] = v;
    __syncthreads();
    #pragma unroll
    for (int off = 1; off < 256; off <<= 1) {
        int p = (t >= off) ? tmp[t - off] : 0;
        __syncthreads();
        tmp[t] += p;
        __syncthreads();
    }
    a[i] = tmp[t] - v;  // exclusive
    if (t == 255) bsum[blockIdx.x] = tmp[255];
}

__global__ void k_scan2(int* __restrict__ bsum) {
    __shared__ int tmp[512];
    int t = threadIdx.x;
    int v = (t < NBLK_SCAN) ? bsum[t] : 0;
    tmp[t] = v;
    __syncthreads();
    #pragma unroll
    for (int off = 1; off < 512; off <<= 1) {
        int p = (t >= off) ? tmp[t - off] : 0;
        __syncthreads();
        tmp[t] += p;
        __syncthreads();
    }
    if (t < NBLK_SCAN) bsum[t] = tmp[t] - v;
}

__global__ void k_scan3(int* __restrict__ a, const int* __restrict__ bsum) {
    int i = blockIdx.x * 256 + threadIdx.x;
    a[i] += bsum[blockIdx.x];
}

// ---------------------------------------------------------------------------
// P3: scatter edges into bin-grouped ebuf; each (block,bin) range is exclusive
// packed entry: src*256 | (dst & 255)
// ---------------------------------------------------------------------------
__launch_bounds__(256)
__global__ void k_scatter_bins(const int* __restrict__ src, const int* __restrict__ dst,
                               const int* __restrict__ off2,
                               unsigned int* __restrict__ ebuf) {
    __shared__ int cursor[NBIN];
    for (int k = threadIdx.x; k < NBIN; k += 256)
        cursor[k] = off2[k * NBLK3 + blockIdx.x];
    __syncthreads();
    int base = blockIdx.x * CHUNK;
    for (int i = threadIdx.x; i < CHUNK; i += 256) {
        int s = src[base + i], d = dst[base + i];
        int pos = atomicAdd(&cursor[d >> 8], 1);
        ebuf[pos] = ((unsigned)s << 8) | (unsigned)(d & 255);
    }
}

// ---------------------------------------------------------------------------
// P4: fine counting-sort within each bin (all in LDS), coalesced esrc output;
// fuses deg -> dinv and rowstart production.
// ---------------------------------------------------------------------------
__launch_bounds__(256)
__global__ void k_fine(const unsigned int* __restrict__ ebuf, const int* __restrict__ off2,
                       int* __restrict__ esrc, int* __restrict__ rowstart,
                       float* __restrict__ dinv) {
    __shared__ int hist[256];
    __shared__ int tmp[256];
    __shared__ int nodeoff[256];
    __shared__ int cursor[256];
    __shared__ unsigned int ed[CAP];
    __shared__ int sOut[CAP];

    const int k = blockIdx.x;
    const int t = threadIdx.x;
    const int e0 = off2[k * NBLK3];
    const int e1 = (k + 1 < NBIN) ? off2[(k + 1) * NBLK3] : N_EDGES;
    int m = e1 - e0;
    if (m > CAP) m = CAP;  // safety clamp (statistically unreachable)

    hist[t] = 0;
    __syncthreads();
    for (int i = t; i < m; i += 256) {
        unsigned v = ebuf[e0 + i];
        ed[i] = v;
        atomicAdd(&hist[v & 255], 1);
    }
    __syncthreads();

    // exclusive scan of hist -> nodeoff
    int v = hist[t];
    tmp[t] = v;
    __syncthreads();
    #pragma unroll
    for (int off = 1; off < 256; off <<= 1) {
        int p = (t >= off) ? tmp[t - off] : 0;
        __syncthreads();
        tmp[t] += p;
        __syncthreads();
    }
    nodeoff[t] = tmp[t] - v;
    cursor[t] = tmp[t] - v;
    __syncthreads();

    // place src values by node
    for (int i = t; i < m; i += 256) {
        unsigned e = ed[i];
        int pos = atomicAdd(&cursor[e & 255], 1);
        sOut[pos] = (int)(e >> 8);
    }
    __syncthreads();

    // stream out coalesced
    for (int i = t; i < m; i += 256) esrc[e0 + i] = sOut[i];

    int n = k * 256 + t;
    if (n < N_NODES) {
        rowstart[n] = e0 + nodeoff[t];
        dinv[n] = rsqrtf((float)hist[t] + 1.0f);
    }
    if (k == 0 && t == 0) rowstart[N_NODES] = N_EDGES;
}

// ---------------------------------------------------------------------------
// GEMM1 (bf16 MFMA): H[M][128] = bf16(X[M][256]) @ bf16(W1[256][128])
// W1 staged ONCE per block into a 64KB XOR-swizzled LDS image; A fragments
// loaded directly global->reg. ZERO barriers in the K loop.
// Wave w owns rows row0 + w*32 .. +31, ALL 128 cols (acc[2][8]).
// ---------------------------------------------------------------------------
// Bs logical layout: [col][k], col 0..127, k 0..255 (bf16). Swizzle: XOR k by
// (col&7)*8 so the 16B fragment reads of 16 different cols spread across all
// bank groups (col stride 512B would otherwise alias to one bank group).
__device__ __forceinline__ int bsw1(int c, int kk) {
    return c * 256 + (kk ^ ((c & 7) << 3));
}

__launch_bounds__(256, 2)
__global__ void k_gemm1(const float* __restrict__ X, const float* __restrict__ W1,
                        __bf16* __restrict__ H) {
    __shared__ __attribute__((aligned(16))) __bf16 Bs[128 * 256];  // 64 KB

    const int t = threadIdx.x;
    const int wave = t >> 6;
    const int lane = t & 63;
    const int lm = lane & 15;
    const int q = lane >> 4;
    const int row0 = blockIdx.x * 128;

    // stage W1 (f32 [k=256][col=128]) -> Bs bf16 [col][k], swizzled. Once.
    for (int i = t; i < 256 * 32; i += 256) {   // 8192 float4 reads
        int kk = i >> 5;          // 0..255
        int c4 = (i & 31) * 4;    // col group
        float4 v = *(const float4*)&W1[kk * HIDDEN + c4];
        Bs[bsw1(c4 + 0, kk)] = (__bf16)v.x;
        Bs[bsw1(c4 + 1, kk)] = (__bf16)v.y;
        Bs[bsw1(c4 + 2, kk)] = (__bf16)v.z;
        Bs[bsw1(c4 + 3, kk)] = (__bf16)v.w;
    }
    __syncthreads();   // the only barrier in this kernel

    f32x4 acc[2][8] = {};

    #pragma unroll
    for (int k0 = 0; k0 < IN_DIM; k0 += 32) {
        bf16x8 af[2];
        #pragma unroll
        for (int mi = 0; mi < 2; ++mi) {
            int g = row0 + wave * 32 + mi * 16 + lm;
            float4 v0 = make_float4(0.f, 0.f, 0.f, 0.f), v1 = v0;
            if (g < N_NODES) {
                const float* p = &X[(size_t)g * IN_DIM + k0 + q * 8];
                v0 = *(const float4*)p;
                v1 = *(const float4*)(p + 4);
            }
            bf16x8 a;
            a[0] = (__bf16)v0.x; a[1] = (__bf16)v0.y;
            a[2] = (__bf16)v0.z; a[3] = (__bf16)v0.w;
            a[4] = (__bf16)v1.x; a[5] = (__bf16)v1.y;
            a[6] = (__bf16)v1.z; a[7] = (__bf16)v1.w;
            af[mi] = a;
        }
        #pragma unroll
        for (int ni = 0; ni < 8; ++ni) {
            bf16x8 bfr = *(const bf16x8*)&Bs[bsw1(ni * 16 + lm, k0 + q * 8)];
            #pragma unroll
            for (int mi = 0; mi < 2; ++mi)
                acc[mi][ni] = __builtin_amdgcn_mfma_f32_16x16x32_bf16(
                    af[mi], bfr, acc[mi][ni], 0, 0, 0);
        }
    }

    #pragma unroll
    for (int mi = 0; mi < 2; ++mi) {
        #pragma unroll
        for (int r = 0; r < 4; ++r) {
            int grow = row0 + wave * 32 + mi * 16 + q * 4 + r;
            if (grow < N_NODES) {
                #pragma unroll
                for (int ni = 0; ni < 8; ++ni)
                    H[grow * HIDDEN + ni * 16 + lm] = (__bf16)acc[mi][ni][r];
            }
        }
    }
}

// ---------------------------------------------------------------------------
// gather layer1: AGG[n] = bf16(relu( sum coef*H[src] + dinv^2*H[n] + b1 ))
// ---------------------------------------------------------------------------
__launch_bounds__(256)
__global__ void k_gather1(const int* __restrict__ rowstart, const int* __restrict__ esrc,
                          const float* __restrict__ dinv,
                          const __bf16* __restrict__ H, const float* __restrict__ b1,
                          __bf16* __restrict__ AGG) {
    int n = blockIdx.x * 16 + (threadIdx.x >> 4);
    if (n >= N_NODES) return;
    int j = (threadIdx.x & 15) * 8;

    float dn = dinv[n];
    float s = dn * dn;
    bf16x8 h = *(const bf16x8*)&H[n * HIDDEN + j];
    float acc[8];
    #pragma unroll
    for (int i = 0; i < 8; ++i) acc[i] = (float)h[i] * s;

    int p0 = rowstart[n], p1 = rowstart[n + 1];
    int p = p0;
    for (; p + 3 < p1; p += 4) {
        int s0 = esrc[p + 0], s1 = esrc[p + 1], s2 = esrc[p + 2], s3 = esrc[p + 3];
        float c0 = dinv[s0] * dn, c1 = dinv[s1] * dn;
        float c2 = dinv[s2] * dn, c3 = dinv[s3] * dn;
        bf16x8 v0 = *(const bf16x8*)&H[s0 * HIDDEN + j];
        bf16x8 v1 = *(const bf16x8*)&H[s1 * HIDDEN + j];
        bf16x8 v2 = *(const bf16x8*)&H[s2 * HIDDEN + j];
        bf16x8 v3 = *(const bf16x8*)&H[s3 * HIDDEN + j];
        #pragma unroll
        for (int i = 0; i < 8; ++i) acc[i] = fmaf((float)v0[i], c0, acc[i]);
        #pragma unroll
        for (int i = 0; i < 8; ++i) acc[i] = fmaf((float)v1[i], c1, acc[i]);
        #pragma unroll
        for (int i = 0; i < 8; ++i) acc[i] = fmaf((float)v2[i], c2, acc[i]);
        #pragma unroll
        for (int i = 0; i < 8; ++i) acc[i] = fmaf((float)v3[i], c3, acc[i]);
    }
    for (; p < p1; ++p) {
        int sidx = esrc[p];
        float c = dinv[sidx] * dn;
        bf16x8 v = *(const bf16x8*)&H[sidx * HIDDEN + j];
        #pragma unroll
        for (int i = 0; i < 8; ++i) acc[i] = fmaf((float)v[i], c, acc[i]);
    }

    float4 bb0 = *(const float4*)&b1[j];
    float4 bb1 = *(const float4*)&b1[j + 4];
    bf16x8 o;
    o[0] = (__bf16)fmaxf(acc[0] + bb0.x, 0.f);
    o[1] = (__bf16)fmaxf(acc[1] + bb0.y, 0.f);
    o[2] = (__bf16)fmaxf(acc[2] + bb0.z, 0.f);
    o[3] = (__bf16)fmaxf(acc[3] + bb0.w, 0.f);
    o[4] = (__bf16)fmaxf(acc[4] + bb1.x, 0.f);
    o[5] = (__bf16)fmaxf(acc[5] + bb1.y, 0.f);
    o[6] = (__bf16)fmaxf(acc[6] + bb1.z, 0.f);
    o[7] = (__bf16)fmaxf(acc[7] + bb1.w, 0.f);
    *(bf16x8*)&AGG[n * HIDDEN + j] = o;
}

// ---------------------------------------------------------------------------
// GEMM2 (bf16 MFMA): H2[M][64] = AGG[M][128] @ bf16(W2[128][64])
// Same structure as gemm1: W2 staged once (16KB LDS, swizzled), A direct
// global->reg (already bf16), barrier-free K loop.
// ---------------------------------------------------------------------------
__device__ __forceinline__ int bsw2(int c, int kk) {
    return c * 128 + (kk ^ ((c & 7) << 3));
}

__launch_bounds__(256, 2)
__global__ void k_gemm2(const __bf16* __restrict__ AGG, const float* __restrict__ W2,
                        __bf16* __restrict__ H2) {
    __shared__ __attribute__((aligned(16))) __bf16 Bs[64 * 128];  // 16 KB

    const int t = threadIdx.x;
    const int wave = t >> 6;
    const int lane = t & 63;
    const int lm = lane & 15;
    const int q = lane >> 4;
    const int row0 = blockIdx.x * 128;

    // stage W2 (f32 [k=128][col=64]) -> Bs bf16 [col][k], swizzled. Once.
    for (int i = t; i < 128 * 16; i += 256) {   // 2048 float4 reads
        int kk = i >> 4;          // 0..127
        int c4 = (i & 15) * 4;
        float4 v = *(const float4*)&W2[kk * OUT_DIM + c4];
        Bs[bsw2(c4 + 0, kk)] = (__bf16)v.x;
        Bs[bsw2(c4 + 1, kk)] = (__bf16)v.y;
        Bs[bsw2(c4 + 2, kk)] = (__bf16)v.z;
        Bs[bsw2(c4 + 3, kk)] = (__bf16)v.w;
    }
    __syncthreads();   // only barrier

    f32x4 acc[2][4] = {};

    #pragma unroll
    for (int k0 = 0; k0 < HIDDEN; k0 += 32) {
        bf16x8 af[2];
        #pragma unroll
        for (int mi = 0; mi < 2; ++mi) {
            int g = row0 + wave * 32 + mi * 16 + lm;
            bf16x8 a = {};
            if (g < N_NODES)
                a = *(const bf16x8*)&AGG[(size_t)g * HIDDEN + k0 + q * 8];
            af[mi] = a;
        }
        #pragma unroll
        for (int ni = 0; ni < 4; ++ni) {
            bf16x8 bfr = *(const bf16x8*)&Bs[bsw2(ni * 16 + lm, k0 + q * 8)];
            #pragma unroll
            for (int mi = 0; mi < 2; ++mi)
                acc[mi][ni] = __builtin_amdgcn_mfma_f32_16x16x32_bf16(
                    af[mi], bfr, acc[mi][ni], 0, 0, 0);
        }
    }

    #pragma unroll
    for (int mi = 0; mi < 2; ++mi) {
        #pragma unroll
        for (int r = 0; r < 4; ++r) {
            int grow = row0 + wave * 32 + mi * 16 + q * 4 + r;
            if (grow < N_NODES) {
                #pragma unroll
                for (int ni = 0; ni < 4; ++ni)
                    H2[grow * OUT_DIM + ni * 16 + lm] = (__bf16)acc[mi][ni][r];
            }
        }
    }
}

// ---------------------------------------------------------------------------
// gather layer2: OUT[n] = relu( sum coef*H2[src] + dinv^2*H2[n] + b2 )  (f32 out)
// ---------------------------------------------------------------------------
__launch_bounds__(256)
__global__ void k_gather2(const int* __restrict__ rowstart, const int* __restrict__ esrc,
                          const float* __restrict__ dinv,
                          const __bf16* __restrict__ H2, const float* __restrict__ b2,
                          float* __restrict__ OUT) {
    int n = blockIdx.x * 32 + (threadIdx.x >> 3);
    if (n >= N_NODES) return;
    int j = (threadIdx.x & 7) * 8;

    float dn = dinv[n];
    float s = dn * dn;
    bf16x8 h = *(const bf16x8*)&H2[n * OUT_DIM + j];
    float acc[8];
    #pragma unroll
    for (int i = 0; i < 8; ++i) acc[i] = (float)h[i] * s;

    int p0 = rowstart[n], p1 = rowstart[n + 1];
    int p = p0;
    for (; p + 3 < p1; p += 4) {
        int s0 = esrc[p + 0], s1 = esrc[p + 1], s2 = esrc[p + 2], s3 = esrc[p + 3];
        float c0 = dinv[s0] * dn, c1 = dinv[s1] * dn;
        float c2 = dinv[s2] * dn, c3 = dinv[s3] * dn;
        bf16x8 v0 = *(const bf16x8*)&H2[s0 * OUT_DIM + j];
        bf16x8 v1 = *(const bf16x8*)&H2[s1 * OUT_DIM + j];
        bf16x8 v2 = *(const bf16x8*)&H2[s2 * OUT_DIM + j];
        bf16x8 v3 = *(const bf16x8*)&H2[s3 * OUT_DIM + j];
        #pragma unroll
        for (int i = 0; i < 8; ++i) acc[i] = fmaf((float)v0[i], c0, acc[i]);
        #pragma unroll
        for (int i = 0; i < 8; ++i) acc[i] = fmaf((float)v1[i], c1, acc[i]);
        #pragma unroll
        for (int i = 0; i < 8; ++i) acc[i] = fmaf((float)v2[i], c2, acc[i]);
        #pragma unroll
        for (int i = 0; i < 8; ++i) acc[i] = fmaf((float)v3[i], c3, acc[i]);
    }
    for (; p < p1; ++p) {
        int sidx = esrc[p];
        float c = dinv[sidx] * dn;
        bf16x8 v = *(const bf16x8*)&H2[sidx * OUT_DIM + j];
        #pragma unroll
        for (int i = 0; i < 8; ++i) acc[i] = fmaf((float)v[i], c, acc[i]);
    }

    float4 bb0 = *(const float4*)&b2[j];
    float4 bb1 = *(const float4*)&b2[j + 4];
    float4 o0, o1;
    o0.x = fmaxf(acc[0] + bb0.x, 0.f);
    o0.y = fmaxf(acc[1] + bb0.y, 0.f);
    o0.z = fmaxf(acc[2] + bb0.z, 0.f);
    o0.w = fmaxf(acc[3] + bb0.w, 0.f);
    o1.x = fmaxf(acc[4] + bb1.x, 0.f);
    o1.y = fmaxf(acc[5] + bb1.y, 0.f);
    o1.z = fmaxf(acc[6] + bb1.z, 0.f);
    o1.w = fmaxf(acc[7] + bb1.w, 0.f);
    *(float4*)&OUT[n * OUT_DIM + j] = o0;
    *(float4*)&OUT[n * OUT_DIM + j + 4] = o1;
}

extern "C" void kernel_launch(void* const* d_in, const int* in_sizes, int n_in,
                              void* d_out, int out_size, void* d_ws, size_t ws_size,
                              hipStream_t stream) {
    const float* x  = (const float*)d_in[0];
    const int* ei   = (const int*)d_in[1];
    const float* W1 = (const float*)d_in[2];
    const float* b1 = (const float*)d_in[3];
    const float* W2 = (const float*)d_in[4];
    const float* b2 = (const float*)d_in[5];
    float* out = (float*)d_out;

    const int* src = ei;
    const int* dst = ei + N_EDGES;

    char* ws = (char*)d_ws;
    int*          cnt2     = (int*)         (ws + 0x000000);   // 400,384 B (becomes off2)
    int*          bsum     = (int*)         (ws + 0x080000);   // 1,564 B
    int*          rowstart = (int*)         (ws + 0x090000);   // 400,004 B
    float*        dinv     = (float*)       (ws + 0x100000);   // 400,000 B
    unsigned int* ebuf     = (unsigned int*)(ws + 0x180000);   // 6.4 MB
    int*          esrc     = (int*)         (ws + 0x800000);   // 6.4 MB
    __bf16*       h1       = (__bf16*)      (ws + 0xE80000);   // 25.6 MB
    __bf16*       agg1     = (__bf16*)      (ws + 0x2880000);  // 25.6 MB
    __bf16*       h2       = (__bf16*)      (ws + 0x4280000);  // 12.8 MB

    // CSR build (two-level counting sort; no random global scatters)
    k_hist<<<NBLK3, 256, 0, stream>>>(dst, cnt2);
    k_scan1<<<NBLK_SCAN, 256, 0, stream>>>(cnt2, bsum);
    k_scan2<<<1, 512, 0, stream>>>(bsum);
    k_scan3<<<NBLK_SCAN, 256, 0, stream>>>(cnt2, bsum);
    k_scatter_bins<<<NBLK3, 256, 0, stream>>>(src, dst, cnt2, ebuf);
    k_fine<<<NBIN, 256, 0, stream>>>(ebuf, cnt2, esrc, rowstart, dinv);

    // layer 1
    k_gemm1<<<(N_NODES + 127) / 128, 256, 0, stream>>>(x, W1, h1);
    k_gather1<<<(N_NODES + 15) / 16, 256, 0, stream>>>(rowstart, esrc, dinv, h1, b1, agg1);
    // layer 2
    k_gemm2<<<(N_NODES + 127) / 128, 256, 0, stream>>>(agg1, W2, h2);
    k_gather2<<<(N_NODES + 31) / 32, 256, 0, stream>>>(rowstart, esrc, dinv, h2, b2, out);
}

// Round 2
// 335.212 us; speedup vs baseline: 1.0901x; 1.0901x over previous
//
#include <hip/hip_runtime.h>

#define N_NODES 100000
#define N_EDGES 1600000
#define IN_DIM 256
#define HIDDEN 128
#define OUT_DIM 64

#define NBIN 391       // coarse bins of 256 nodes: ceil(100000/256)
#define NBLK3 256      // histogram/scatter blocks
#define CHUNK 6250     // edges per block: N_EDGES / NBLK3 exactly
#define NMAT (NBIN * NBLK3)      // 100096 = scan length
#define NBLK_SCAN (NMAT / 256)   // 391 exactly
#define CAP 6144       // max edges per bin (mean 4096, sigma 64 -> 32 sigma margin)

typedef __bf16 bf16x8 __attribute__((ext_vector_type(8)));
typedef __bf16 bf16x4 __attribute__((ext_vector_type(4)));
typedef float f32x4 __attribute__((ext_vector_type(4)));

// ---------------------------------------------------------------------------
// P1: per-(bin,block) histogram. cnt2[k*NBLK3 + b] = #edges of block b in bin k
// ---------------------------------------------------------------------------
__launch_bounds__(256)
__global__ void k_hist(const int* __restrict__ dst, int* __restrict__ cnt2) {
    __shared__ int hist[NBIN];
    for (int i = threadIdx.x; i < NBIN; i += 256) hist[i] = 0;
    __syncthreads();
    int base = blockIdx.x * CHUNK;
    for (int i = threadIdx.x; i < CHUNK; i += 256)
        atomicAdd(&hist[dst[base + i] >> 8], 1);
    __syncthreads();
    for (int k = threadIdx.x; k < NBIN; k += 256)
        cnt2[k * NBLK3 + blockIdx.x] = hist[k];
}

// ---------------------------------------------------------------------------
// P2: 3-kernel exclusive scan over cnt2 (in place), length NMAT
// ---------------------------------------------------------------------------
__global__ void k_scan1(int* __restrict__ a, int* __restrict__ bsum) {
    __shared__ int tmp[256];
    int t = threadIdx.x;
    int i = blockIdx.x * 256 + t;
    int v = a[i];
    tmp[t] = v;
    __syncthreads();
    #pragma unroll
    for (int off = 1; off < 256; off <<= 1) {
        int p = (t >= off) ? tmp[t - off] : 0;
        __syncthreads();
        tmp[t] += p;
        __syncthreads();
    }
    a[i] = tmp[t] - v;  // exclusive
    if (t == 255) bsum[blockIdx.x] = tmp[255];
}

__global__ void k_scan2(int* __restrict__ bsum) {
    __shared__ int tmp[512];
    int t = threadIdx.x;
    int v = (t < NBLK_SCAN) ? bsum[t] : 0;
    tmp[t] = v;
    __syncthreads();
    #pragma unroll
    for (int off = 1; off < 512; off <<= 1) {
        int p = (t >= off) ? tmp[t - off] : 0;
        __syncthreads();
        tmp[t] += p;
        __syncthreads();
    }
    if (t < NBLK_SCAN) bsum[t] = tmp[t] - v;
}

__global__ void k_scan3(int* __restrict__ a, const int* __restrict__ bsum) {
    int i = blockIdx.x * 256 + threadIdx.x;
    a[i] += bsum[blockIdx.x];
}

// ---------------------------------------------------------------------------
// P3: scatter edges into bin-grouped ebuf; each (block,bin) range is exclusive
// packed entry: src*256 | (dst & 255)
// ---------------------------------------------------------------------------
__launch_bounds__(256)
__global__ void k_scatter_bins(const int* __restrict__ src, const int* __restrict__ dst,
                               const int* __restrict__ off2,
                               unsigned int* __restrict__ ebuf) {
    __shared__ int cursor[NBIN];
    for (int k = threadIdx.x; k < NBIN; k += 256)
        cursor[k] = off2[k * NBLK3 + blockIdx.x];
    __syncthreads();
    int base = blockIdx.x * CHUNK;
    for (int i = threadIdx.x; i < CHUNK; i += 256) {
        int s = src[base + i], d = dst[base + i];
        int pos = atomicAdd(&cursor[d >> 8], 1);
        ebuf[pos] = ((unsigned)s << 8) | (unsigned)(d & 255);
    }
}

// ---------------------------------------------------------------------------
// P4: fine counting-sort within each bin (all in LDS), coalesced esrc output;
// fuses deg -> dinv and rowstart production.
// ---------------------------------------------------------------------------
__launch_bounds__(256)
__global__ void k_fine(const unsigned int* __restrict__ ebuf, const int* __restrict__ off2,
                       int* __restrict__ esrc, int* __restrict__ rowstart,
                       float* __restrict__ dinv) {
    __shared__ int hist[256];
    __shared__ int tmp[256];
    __shared__ int nodeoff[256];
    __shared__ int cursor[256];
    __shared__ unsigned int ed[CAP];
    __shared__ int sOut[CAP];

    const int k = blockIdx.x;
    const int t = threadIdx.x;
    const int e0 = off2[k * NBLK3];
    const int e1 = (k + 1 < NBIN) ? off2[(k + 1) * NBLK3] : N_EDGES;
    int m = e1 - e0;
    if (m > CAP) m = CAP;  // safety clamp (statistically unreachable)

    hist[t] = 0;
    __syncthreads();
    for (int i = t; i < m; i += 256) {
        unsigned v = ebuf[e0 + i];
        ed[i] = v;
        atomicAdd(&hist[v & 255], 1);
    }
    __syncthreads();

    // exclusive scan of hist -> nodeoff
    int v = hist[t];
    tmp[t] = v;
    __syncthreads();
    #pragma unroll
    for (int off = 1; off < 256; off <<= 1) {
        int p = (t >= off) ? tmp[t - off] : 0;
        __syncthreads();
        tmp[t] += p;
        __syncthreads();
    }
    nodeoff[t] = tmp[t] - v;
    cursor[t] = tmp[t] - v;
    __syncthreads();

    // place src values by node
    for (int i = t; i < m; i += 256) {
        unsigned e = ed[i];
        int pos = atomicAdd(&cursor[e & 255], 1);
        sOut[pos] = (int)(e >> 8);
    }
    __syncthreads();

    // stream out coalesced
    for (int i = t; i < m; i += 256) esrc[e0 + i] = sOut[i];

    int n = k * 256 + t;
    if (n < N_NODES) {
        rowstart[n] = e0 + nodeoff[t];
        dinv[n] = rsqrtf((float)hist[t] + 1.0f);
    }
    if (k == 0 && t == 0) rowstart[N_NODES] = N_EDGES;
}

// ---------------------------------------------------------------------------
// GEMM1 (bf16 MFMA): H[M][128] = bf16(X[M][256]) @ bf16(W1[256][128])
// 512 threads (8 waves), 256 rows/block, grid 391. W1 staged ONCE:
//   - column-major coalesced f32 reads (consecutive lanes = consecutive cols)
//   - ONE ds_write_b128 per (col, kgroup), slots rotate (kg ^ (c&7)) -> no
//     bank conflicts on the write side.
// A fragments direct global->reg. Barrier-free fully-unrolled K loop.
// Wave w owns rows 32w..32w+31, ALL 128 cols (acc[2][8]).
// ---------------------------------------------------------------------------
// Bs layout: [col][k] with XOR swizzle on the 8k-group: elem = c*256 + (kk ^ ((c&7)<<3))
__device__ __forceinline__ int bsw1(int c, int kk) {
    return c * 256 + (kk ^ ((c & 7) << 3));
}

__launch_bounds__(512, 4)
__global__ void k_gemm1(const float* __restrict__ X, const float* __restrict__ W1,
                        __bf16* __restrict__ H) {
    __shared__ __attribute__((aligned(16))) __bf16 Bs[128 * 256];  // 64 KB

    const int t = threadIdx.x;
    const int wave = t >> 6;
    const int lane = t & 63;
    const int lm = lane & 15;
    const int q = lane >> 4;
    const int row0 = blockIdx.x * 256;

    // stage W1 -> Bs bf16 [col][k] swizzled, b128 writes, coalesced reads
    for (int p = 0; p < 8; ++p) {
        int i = t + 512 * p;        // 0..4095
        int c = i & 127;            // column
        int kg = i >> 7;            // k-group 0..31
        float v[8];
        #pragma unroll
        for (int j = 0; j < 8; ++j)
            v[j] = W1[(kg * 8 + j) * HIDDEN + c];
        bf16x8 w;
        #pragma unroll
        for (int j = 0; j < 8; ++j) w[j] = (__bf16)v[j];
        *(bf16x8*)&Bs[bsw1(c, kg * 8)] = w;
    }
    __syncthreads();   // the only barrier

    f32x4 acc[2][8] = {};

    #pragma unroll
    for (int k0 = 0; k0 < IN_DIM; k0 += 32) {
        bf16x8 af[2];
        #pragma unroll
        for (int mi = 0; mi < 2; ++mi) {
            int g = row0 + wave * 32 + mi * 16 + lm;
            float4 v0 = make_float4(0.f, 0.f, 0.f, 0.f), v1 = v0;
            if (g < N_NODES) {
                const float* p = &X[(size_t)g * IN_DIM + k0 + q * 8];
                v0 = *(const float4*)p;
                v1 = *(const float4*)(p + 4);
            }
            bf16x8 a;
            a[0] = (__bf16)v0.x; a[1] = (__bf16)v0.y;
            a[2] = (__bf16)v0.z; a[3] = (__bf16)v0.w;
            a[4] = (__bf16)v1.x; a[5] = (__bf16)v1.y;
            a[6] = (__bf16)v1.z; a[7] = (__bf16)v1.w;
            af[mi] = a;
        }
        #pragma unroll
        for (int ni = 0; ni < 8; ++ni) {
            bf16x8 bfr = *(const bf16x8*)&Bs[bsw1(ni * 16 + lm, k0 + q * 8)];
            #pragma unroll
            for (int mi = 0; mi < 2; ++mi)
                acc[mi][ni] = __builtin_amdgcn_mfma_f32_16x16x32_bf16(
                    af[mi], bfr, acc[mi][ni], 0, 0, 0);
        }
    }

    #pragma unroll
    for (int mi = 0; mi < 2; ++mi) {
        #pragma unroll
        for (int r = 0; r < 4; ++r) {
            int grow = row0 + wave * 32 + mi * 16 + q * 4 + r;
            if (grow < N_NODES) {
                #pragma unroll
                for (int ni = 0; ni < 8; ++ni)
                    H[grow * HIDDEN + ni * 16 + lm] = (__bf16)acc[mi][ni][r];
            }
        }
    }
}

// ---------------------------------------------------------------------------
// gather layer1: AGG[n] = bf16(relu( sum coef*H[src] + dinv^2*H[n] + b1 ))
// ---------------------------------------------------------------------------
__launch_bounds__(256)
__global__ void k_gather1(const int* __restrict__ rowstart, const int* __restrict__ esrc,
                          const float* __restrict__ dinv,
                          const __bf16* __restrict__ H, const float* __restrict__ b1,
                          __bf16* __restrict__ AGG) {
    int n = blockIdx.x * 16 + (threadIdx.x >> 4);
    if (n >= N_NODES) return;
    int j = (threadIdx.x & 15) * 8;

    float dn = dinv[n];
    float s = dn * dn;
    bf16x8 h = *(const bf16x8*)&H[n * HIDDEN + j];
    float acc[8];
    #pragma unroll
    for (int i = 0; i < 8; ++i) acc[i] = (float)h[i] * s;

    int p0 = rowstart[n], p1 = rowstart[n + 1];
    int p = p0;
    for (; p + 3 < p1; p += 4) {
        int s0 = esrc[p + 0], s1 = esrc[p + 1], s2 = esrc[p + 2], s3 = esrc[p + 3];
        float c0 = dinv[s0] * dn, c1 = dinv[s1] * dn;
        float c2 = dinv[s2] * dn, c3 = dinv[s3] * dn;
        bf16x8 v0 = *(const bf16x8*)&H[s0 * HIDDEN + j];
        bf16x8 v1 = *(const bf16x8*)&H[s1 * HIDDEN + j];
        bf16x8 v2 = *(const bf16x8*)&H[s2 * HIDDEN + j];
        bf16x8 v3 = *(const bf16x8*)&H[s3 * HIDDEN + j];
        #pragma unroll
        for (int i = 0; i < 8; ++i) acc[i] = fmaf((float)v0[i], c0, acc[i]);
        #pragma unroll
        for (int i = 0; i < 8; ++i) acc[i] = fmaf((float)v1[i], c1, acc[i]);
        #pragma unroll
        for (int i = 0; i < 8; ++i) acc[i] = fmaf((float)v2[i], c2, acc[i]);
        #pragma unroll
        for (int i = 0; i < 8; ++i) acc[i] = fmaf((float)v3[i], c3, acc[i]);
    }
    for (; p < p1; ++p) {
        int sidx = esrc[p];
        float c = dinv[sidx] * dn;
        bf16x8 v = *(const bf16x8*)&H[sidx * HIDDEN + j];
        #pragma unroll
        for (int i = 0; i < 8; ++i) acc[i] = fmaf((float)v[i], c, acc[i]);
    }

    float4 bb0 = *(const float4*)&b1[j];
    float4 bb1 = *(const float4*)&b1[j + 4];
    bf16x8 o;
    o[0] = (__bf16)fmaxf(acc[0] + bb0.x, 0.f);
    o[1] = (__bf16)fmaxf(acc[1] + bb0.y, 0.f);
    o[2] = (__bf16)fmaxf(acc[2] + bb0.z, 0.f);
    o[3] = (__bf16)fmaxf(acc[3] + bb0.w, 0.f);
    o[4] = (__bf16)fmaxf(acc[4] + bb1.x, 0.f);
    o[5] = (__bf16)fmaxf(acc[5] + bb1.y, 0.f);
    o[6] = (__bf16)fmaxf(acc[6] + bb1.z, 0.f);
    o[7] = (__bf16)fmaxf(acc[7] + bb1.w, 0.f);
    *(bf16x8*)&AGG[n * HIDDEN + j] = o;
}

// ---------------------------------------------------------------------------
// GEMM2 (bf16 MFMA): H2[M][64] = AGG[M][128] @ bf16(W2[128][64])
// Same structure as gemm1; W2 image is 16 KB.
// ---------------------------------------------------------------------------
__device__ __forceinline__ int bsw2(int c, int kk) {
    return c * 128 + (kk ^ ((c & 7) << 3));
}

__launch_bounds__(512, 4)
__global__ void k_gemm2(const __bf16* __restrict__ AGG, const float* __restrict__ W2,
                        __bf16* __restrict__ H2) {
    __shared__ __attribute__((aligned(16))) __bf16 Bs[64 * 128];  // 16 KB

    const int t = threadIdx.x;
    const int wave = t >> 6;
    const int lane = t & 63;
    const int lm = lane & 15;
    const int q = lane >> 4;
    const int row0 = blockIdx.x * 256;

    // stage W2 -> Bs bf16 [col][k] swizzled, b128 writes, coalesced reads
    for (int p = 0; p < 2; ++p) {
        int i = t + 512 * p;        // 0..1023
        int c = i & 63;             // column
        int kg = i >> 6;            // k-group 0..15
        float v[8];
        #pragma unroll
        for (int j = 0; j < 8; ++j)
            v[j] = W2[(kg * 8 + j) * OUT_DIM + c];
        bf16x8 w;
        #pragma unroll
        for (int j = 0; j < 8; ++j) w[j] = (__bf16)v[j];
        *(bf16x8*)&Bs[bsw2(c, kg * 8)] = w;
    }
    __syncthreads();   // only barrier

    f32x4 acc[2][4] = {};

    #pragma unroll
    for (int k0 = 0; k0 < HIDDEN; k0 += 32) {
        bf16x8 af[2];
        #pragma unroll
        for (int mi = 0; mi < 2; ++mi) {
            int g = row0 + wave * 32 + mi * 16 + lm;
            bf16x8 a = {};
            if (g < N_NODES)
                a = *(const bf16x8*)&AGG[(size_t)g * HIDDEN + k0 + q * 8];
            af[mi] = a;
        }
        #pragma unroll
        for (int ni = 0; ni < 4; ++ni) {
            bf16x8 bfr = *(const bf16x8*)&Bs[bsw2(ni * 16 + lm, k0 + q * 8)];
            #pragma unroll
            for (int mi = 0; mi < 2; ++mi)
                acc[mi][ni] = __builtin_amdgcn_mfma_f32_16x16x32_bf16(
                    af[mi], bfr, acc[mi][ni], 0, 0, 0);
        }
    }

    #pragma unroll
    for (int mi = 0; mi < 2; ++mi) {
        #pragma unroll
        for (int r = 0; r < 4; ++r) {
            int grow = row0 + wave * 32 + mi * 16 + q * 4 + r;
            if (grow < N_NODES) {
                #pragma unroll
                for (int ni = 0; ni < 4; ++ni)
                    H2[grow * OUT_DIM + ni * 16 + lm] = (__bf16)acc[mi][ni][r];
            }
        }
    }
}

// ---------------------------------------------------------------------------
// gather layer2: OUT[n] = relu( sum coef*H2[src] + dinv^2*H2[n] + b2 )  (f32 out)
// ---------------------------------------------------------------------------
__launch_bounds__(256)
__global__ void k_gather2(const int* __restrict__ rowstart, const int* __restrict__ esrc,
                          const float* __restrict__ dinv,
                          const __bf16* __restrict__ H2, const float* __restrict__ b2,
                          float* __restrict__ OUT) {
    int n = blockIdx.x * 32 + (threadIdx.x >> 3);
    if (n >= N_NODES) return;
    int j = (threadIdx.x & 7) * 8;

    float dn = dinv[n];
    float s = dn * dn;
    bf16x8 h = *(const bf16x8*)&H2[n * OUT_DIM + j];
    float acc[8];
    #pragma unroll
    for (int i = 0; i < 8; ++i) acc[i] = (float)h[i] * s;

    int p0 = rowstart[n], p1 = rowstart[n + 1];
    int p = p0;
    for (; p + 3 < p1; p += 4) {
        int s0 = esrc[p + 0], s1 = esrc[p + 1], s2 = esrc[p + 2], s3 = esrc[p + 3];
        float c0 = dinv[s0] * dn, c1 = dinv[s1] * dn;
        float c2 = dinv[s2] * dn, c3 = dinv[s3] * dn;
        bf16x8 v0 = *(const bf16x8*)&H2[s0 * OUT_DIM + j];
        bf16x8 v1 = *(const bf16x8*)&H2[s1 * OUT_DIM + j];
        bf16x8 v2 = *(const bf16x8*)&H2[s2 * OUT_DIM + j];
        bf16x8 v3 = *(const bf16x8*)&H2[s3 * OUT_DIM + j];
        #pragma unroll
        for (int i = 0; i < 8; ++i) acc[i] = fmaf((float)v0[i], c0, acc[i]);
        #pragma unroll
        for (int i = 0; i < 8; ++i) acc[i] = fmaf((float)v1[i], c1, acc[i]);
        #pragma unroll
        for (int i = 0; i < 8; ++i) acc[i] = fmaf((float)v2[i], c2, acc[i]);
        #pragma unroll
        for (int i = 0; i < 8; ++i) acc[i] = fmaf((float)v3[i], c3, acc[i]);
    }
    for (; p < p1; ++p) {
        int sidx = esrc[p];
        float c = dinv[sidx] * dn;
        bf16x8 v = *(const bf16x8*)&H2[sidx * OUT_DIM + j];
        #pragma unroll
        for (int i = 0; i < 8; ++i) acc[i] = fmaf((float)v[i], c, acc[i]);
    }

    float4 bb0 = *(const float4*)&b2[j];
    float4 bb1 = *(const float4*)&b2[j + 4];
    float4 o0, o1;
    o0.x = fmaxf(acc[0] + bb0.x, 0.f);
    o0.y = fmaxf(acc[1] + bb0.y, 0.f);
    o0.z = fmaxf(acc[2] + bb0.z, 0.f);
    o0.w = fmaxf(acc[3] + bb0.w, 0.f);
    o1.x = fmaxf(acc[4] + bb1.x, 0.f);
    o1.y = fmaxf(acc[5] + bb1.y, 0.f);
    o1.z = fmaxf(acc[6] + bb1.z, 0.f);
    o1.w = fmaxf(acc[7] + bb1.w, 0.f);
    *(float4*)&OUT[n * OUT_DIM + j] = o0;
    *(float4*)&OUT[n * OUT_DIM + j + 4] = o1;
}

extern "C" void kernel_launch(void* const* d_in, const int* in_sizes, int n_in,
                              void* d_out, int out_size, void* d_ws, size_t ws_size,
                              hipStream_t stream) {
    const float* x  = (const float*)d_in[0];
    const int* ei   = (const int*)d_in[1];
    const float* W1 = (const float*)d_in[2];
    const float* b1 = (const float*)d_in[3];
    const float* W2 = (const float*)d_in[4];
    const float* b2 = (const float*)d_in[5];
    float* out = (float*)d_out;

    const int* src = ei;
    const int* dst = ei + N_EDGES;

    char* ws = (char*)d_ws;
    int*          cnt2     = (int*)         (ws + 0x000000);   // 400,384 B (becomes off2)
    int*          bsum     = (int*)         (ws + 0x080000);   // 1,564 B
    int*          rowstart = (int*)         (ws + 0x090000);   // 400,004 B
    float*        dinv     = (float*)       (ws + 0x100000);   // 400,000 B
    unsigned int* ebuf     = (unsigned int*)(ws + 0x180000);   // 6.4 MB
    int*          esrc     = (int*)         (ws + 0x800000);   // 6.4 MB
    __bf16*       h1       = (__bf16*)      (ws + 0xE80000);   // 25.6 MB
    __bf16*       agg1     = (__bf16*)      (ws + 0x2880000);  // 25.6 MB
    __bf16*       h2       = (__bf16*)      (ws + 0x4280000);  // 12.8 MB

    // CSR build (two-level counting sort; no random global scatters)
    k_hist<<<NBLK3, 256, 0, stream>>>(dst, cnt2);
    k_scan1<<<NBLK_SCAN, 256, 0, stream>>>(cnt2, bsum);
    k_scan2<<<1, 512, 0, stream>>>(bsum);
    k_scan3<<<NBLK_SCAN, 256, 0, stream>>>(cnt2, bsum);
    k_scatter_bins<<<NBLK3, 256, 0, stream>>>(src, dst, cnt2, ebuf);
    k_fine<<<NBIN, 256, 0, stream>>>(ebuf, cnt2, esrc, rowstart, dinv);

    // layer 1  (256 rows per block, 512 threads)
    k_gemm1<<<(N_NODES + 255) / 256, 512, 0, stream>>>(x, W1, h1);
    k_gather1<<<(N_NODES + 15) / 16, 256, 0, stream>>>(rowstart, esrc, dinv, h1, b1, agg1);
    // layer 2
    k_gemm2<<<(N_NODES + 255) / 256, 512, 0, stream>>>(agg1, W2, h2);
    k_gather2<<<(N_NODES + 31) / 32, 256, 0, stream>>>(rowstart, esrc, dinv, h2, b2, out);
}